// Round 1
// baseline (447.316 us; speedup 1.0000x reference)
//
#include <hip/hip_runtime.h>

typedef unsigned short u16;
typedef unsigned int   u32;

typedef float  f32x4  __attribute__((ext_vector_type(4)));
typedef __bf16 bf16x8 __attribute__((ext_vector_type(8)));

#define S_LEN  4096
#define DMODEL 1024
#define NSUB   4
#define DSUB   256
#define HFF    512
#define NTOK   16384   // B*S = 4*4096

static_assert(sizeof(bf16x8) == 16, "frag size");

__device__ __forceinline__ u16 f2bf(float f) {
    union { float f; u32 u; } v; v.f = f;
    u32 r = (v.u + 0x7fffu + ((v.u >> 16) & 1u)) >> 16;   // RNE
    return (u16)r;
}

// ---------------------------------------------------------------- rope table
// cosT/sinT: [4096][512] fp32.  ang = s * 10000^(-2i/1024)
__global__ __launch_bounds__(256) void k_rope(float* __restrict__ cosT,
                                              float* __restrict__ sinT) {
    int idx = blockIdx.x * 256 + threadIdx.x;        // 4096*512 = 2M threads
    int s = idx >> 9, i = idx & 511;
    // C = -2*ln(10000)/1024, computed in double then rounded
    const float C = -0.017988945062455435f;
    float inv = expf(C * (float)i);
    float ang = (float)s * inv;
    float sn, cs;
    sincosf(ang, &sn, &cs);
    cosT[idx] = cs;
    sinT[idx] = sn;
}

// ------------------------------------------------- weight transpose->bf16
// out[b][c][r] = bf16(in[b][r][c]);  in: [Bn][R][C]
__global__ __launch_bounds__(256) void k_wt(const float* __restrict__ in,
                                            u16* __restrict__ out,
                                            int Bn, int R, int C) {
    int idx = blockIdx.x * 256 + threadIdx.x;
    int total = Bn * R * C;
    if (idx >= total) return;
    int b = idx / (R * C);
    int rem = idx % (R * C);
    int c = rem / R;
    int r = rem % R;
    out[idx] = f2bf(in[(size_t)b * R * C + (size_t)r * C + c]);
}

// ---------------------------------------------- fused RMSNorm + RoPE -> bf16
// one block per token, 256 threads; thread t handles d = t, t+256, t+512, t+768
__global__ __launch_bounds__(256) void k_norm_rope(const float* __restrict__ x,
                                                   const float* __restrict__ nw,
                                                   const float* __restrict__ cosT,
                                                   const float* __restrict__ sinT,
                                                   u16* __restrict__ h) {
    int tok = blockIdx.x;
    int s = tok & (S_LEN - 1);
    int t = threadIdx.x;
    const float* xr = x + (size_t)tok * DMODEL;
    float x0 = xr[t], x1 = xr[t + 256], x2 = xr[t + 512], x3 = xr[t + 768];
    float ss = x0 * x0 + x1 * x1 + x2 * x2 + x3 * x3;
#pragma unroll
    for (int o = 32; o > 0; o >>= 1) ss += __shfl_down(ss, o, 64);
    __shared__ float red[4];
    if ((t & 63) == 0) red[t >> 6] = ss;
    __syncthreads();
    float tot = red[0] + red[1] + red[2] + red[3];
    float sc = rsqrtf(tot * (1.0f / DMODEL) + 1e-6f);
    float n0 = x0 * sc * nw[t];
    float n1 = x1 * sc * nw[t + 256];
    float n2 = x2 * sc * nw[t + 512];
    float n3 = x3 * sc * nw[t + 768];
    const float* cr = cosT + (size_t)s * 512;
    const float* sr = sinT + (size_t)s * 512;
    float c0 = cr[t], c1 = cr[t + 256];
    float s0 = sr[t], s1 = sr[t + 256];
    u16* hr = h + (size_t)tok * DMODEL;
    // rotate_half: d<512: h*cos - h[d+512]*sin ; d>=512: h*cos + h[d-512]*sin
    hr[t]       = f2bf(n0 * c0 - n2 * s0);
    hr[t + 256] = f2bf(n1 * c1 - n3 * s1);
    hr[t + 512] = f2bf(n2 * c0 + n0 * s0);
    hr[t + 768] = f2bf(n3 * c1 + n1 * s1);
}

// ---------------------------------------------------------- grouped SwiGLU
// grid: 256 m-blocks x 4 subspaces. block = 256 thr (4 waves, 2x2 wave grid).
// BM=64 tokens. gate/up computed in H-chunks of 128, silu*up -> LDS,
// down accumulated across chunks. dmid written as bf16 [16384][1024].
__global__ __launch_bounds__(256) void k_swiglu(const u16* __restrict__ h,
                                                const u16* __restrict__ wgT,   // [4][512][256]
                                                const u16* __restrict__ wuT,   // [4][512][256]
                                                const u16* __restrict__ wdT,   // [4][256][512]
                                                u16* __restrict__ dmid) {
    int bid = blockIdx.x;
    int mb = bid & 255, n = bid >> 8;
    int m0 = mb * 64;
    int tid = threadIdx.x;
    int lane = tid & 63, wid = tid >> 6;
    int wr = wid >> 1, wc = wid & 1;

    __shared__ u16 sA[64 * 256];   // h tile, swizzled, 32KB
    __shared__ u16 sT[64 * 128];   // silu(g)*u chunk, swizzled, 16KB

    // ---- stage h tile [64][256] (subspace n slice), swizzled
    const u16* hbase = h + (size_t)m0 * DMODEL + n * DSUB;
#pragma unroll
    for (int it = 0; it < 8; ++it) {
        int e = tid * 8 + it * 2048;
        int r = e >> 8, c = e & 255;
        uint4 v = *(const uint4*)(hbase + (size_t)r * DMODEL + c);
        u32 off = ((u32)(r * 512 + c * 2)) ^ ((u32)(r & 7) << 4);
        *(uint4*)((char*)sA + off) = v;
    }

    const f32x4 zero = {0.f, 0.f, 0.f, 0.f};
    f32x4 accd[2][8];
#pragma unroll
    for (int a = 0; a < 2; ++a)
#pragma unroll
        for (int b = 0; b < 8; ++b) accd[a][b] = zero;

    const u16* wg = wgT + (size_t)n * HFF * DSUB;
    const u16* wu = wuT + (size_t)n * HFF * DSUB;
    const u16* wd = wdT + (size_t)n * DSUB * HFF;

    __syncthreads();

#pragma unroll
    for (int hc = 0; hc < 4; ++hc) {
        // ---- gate / up for H-chunk [64 x 128]
        f32x4 accg[2][4], accu[2][4];
#pragma unroll
        for (int a = 0; a < 2; ++a)
#pragma unroll
            for (int b = 0; b < 4; ++b) { accg[a][b] = zero; accu[a][b] = zero; }

#pragma unroll
        for (int ks = 0; ks < 8; ++ks) {
            bf16x8 afr[2];
#pragma unroll
            for (int rt = 0; rt < 2; ++rt) {
                int arow = wr * 32 + rt * 16 + (lane & 15);
                int k0 = ks * 32 + (lane >> 4) * 8;
                u32 off = ((u32)(arow * 512 + k0 * 2)) ^ ((u32)(arow & 7) << 4);
                afr[rt] = *(const bf16x8*)((const char*)sA + off);
            }
#pragma unroll
            for (int ct = 0; ct < 4; ++ct) {
                int hcol = hc * 128 + wc * 64 + ct * 16 + (lane & 15);
                int d0 = ks * 32 + (lane >> 4) * 8;
                bf16x8 bg = *(const bf16x8*)(wg + (size_t)hcol * DSUB + d0);
                bf16x8 bu = *(const bf16x8*)(wu + (size_t)hcol * DSUB + d0);
#pragma unroll
                for (int rt = 0; rt < 2; ++rt) {
                    accg[rt][ct] = __builtin_amdgcn_mfma_f32_16x16x32_bf16(afr[rt], bg, accg[rt][ct], 0, 0, 0);
                    accu[rt][ct] = __builtin_amdgcn_mfma_f32_16x16x32_bf16(afr[rt], bu, accu[rt][ct], 0, 0, 0);
                }
            }
        }

        __syncthreads();   // previous chunk's sT fully consumed

        // ---- t = silu(gate) * up -> sT (swizzled), C-layout scatter
#pragma unroll
        for (int rt = 0; rt < 2; ++rt)
#pragma unroll
            for (int ct = 0; ct < 4; ++ct) {
                int rbase = wr * 32 + rt * 16 + (lane >> 4) * 4;
                int col = wc * 64 + ct * 16 + (lane & 15);
#pragma unroll
                for (int q = 0; q < 4; ++q) {
                    float g = accg[rt][ct][q], u = accu[rt][ct][q];
                    float tv = (g / (1.0f + expf(-g))) * u;
                    int row = rbase + q;
                    u32 off = ((u32)(row * 256 + col * 2)) ^ ((u32)(row & 7) << 4);
                    *(u16*)((char*)sT + off) = f2bf(tv);
                }
            }

        __syncthreads();

        // ---- down accumulation over this chunk's K=128
#pragma unroll
        for (int k2 = 0; k2 < 4; ++k2) {
            bf16x8 afr[2];
#pragma unroll
            for (int rt = 0; rt < 2; ++rt) {
                int arow = wr * 32 + rt * 16 + (lane & 15);
                int k0 = k2 * 32 + (lane >> 4) * 8;
                u32 off = ((u32)(arow * 256 + k0 * 2)) ^ ((u32)(arow & 7) << 4);
                afr[rt] = *(const bf16x8*)((const char*)sT + off);
            }
#pragma unroll
            for (int ct = 0; ct < 8; ++ct) {
                int dcol = wc * 128 + ct * 16 + (lane & 15);
                int h0 = hc * 128 + k2 * 32 + (lane >> 4) * 8;
                bf16x8 bd = *(const bf16x8*)(wd + (size_t)dcol * HFF + h0);
#pragma unroll
                for (int rt = 0; rt < 2; ++rt)
                    accd[rt][ct] = __builtin_amdgcn_mfma_f32_16x16x32_bf16(afr[rt], bd, accd[rt][ct], 0, 0, 0);
            }
        }
    }

    // ---- write dmid [64][256] slice as bf16
#pragma unroll
    for (int rt = 0; rt < 2; ++rt)
#pragma unroll
        for (int ct = 0; ct < 8; ++ct) {
            int rbase = m0 + wr * 32 + rt * 16 + (lane >> 4) * 4;
            int col = n * DSUB + wc * 128 + ct * 16 + (lane & 15);
#pragma unroll
            for (int q = 0; q < 4; ++q)
                dmid[(size_t)(rbase + q) * DMODEL + col] = f2bf(accd[rt][ct][q]);
        }
}

// -------------------------------------------------- final GEMM + residual
// out[m][e] = sum_d dmid[m][d]*Wo[d][e] + x[m][e]
// grid: 256 m-blocks x 8 n-blocks; BM=64, BN=128; 4 waves 2x2.
__global__ __launch_bounds__(256) void k_final(const u16* __restrict__ dmid,
                                               const u16* __restrict__ woT,   // [1024][1024] = [e][d]
                                               const float* __restrict__ x,
                                               float* __restrict__ out) {
    int bid = blockIdx.x;
    int mb = bid & 255, nb = bid >> 8;
    int m0 = mb * 64, n0 = nb * 128;
    int tid = threadIdx.x;
    int lane = tid & 63, wid = tid >> 6;
    int wr = wid >> 1, wc = wid & 1;

    __shared__ u16 sA[64 * 256];   // dmid k-chunk tile, swizzled

    const f32x4 zero = {0.f, 0.f, 0.f, 0.f};
    f32x4 acc[2][4];
#pragma unroll
    for (int a = 0; a < 2; ++a)
#pragma unroll
        for (int b = 0; b < 4; ++b) acc[a][b] = zero;

#pragma unroll
    for (int kc = 0; kc < 4; ++kc) {
        __syncthreads();
        const u16* dbase = dmid + (size_t)m0 * DMODEL + kc * 256;
#pragma unroll
        for (int it = 0; it < 8; ++it) {
            int e = tid * 8 + it * 2048;
            int r = e >> 8, c = e & 255;
            uint4 v = *(const uint4*)(dbase + (size_t)r * DMODEL + c);
            u32 off = ((u32)(r * 512 + c * 2)) ^ ((u32)(r & 7) << 4);
            *(uint4*)((char*)sA + off) = v;
        }
        __syncthreads();

#pragma unroll
        for (int ks = 0; ks < 8; ++ks) {
            bf16x8 afr[2];
#pragma unroll
            for (int rt = 0; rt < 2; ++rt) {
                int arow = wr * 32 + rt * 16 + (lane & 15);
                int k0 = ks * 32 + (lane >> 4) * 8;
                u32 off = ((u32)(arow * 512 + k0 * 2)) ^ ((u32)(arow & 7) << 4);
                afr[rt] = *(const bf16x8*)((const char*)sA + off);
            }
#pragma unroll
            for (int ct = 0; ct < 4; ++ct) {
                int e = n0 + wc * 64 + ct * 16 + (lane & 15);
                int d0 = kc * 256 + ks * 32 + (lane >> 4) * 8;
                bf16x8 b = *(const bf16x8*)(woT + (size_t)e * DMODEL + d0);
#pragma unroll
                for (int rt = 0; rt < 2; ++rt)
                    acc[rt][ct] = __builtin_amdgcn_mfma_f32_16x16x32_bf16(afr[rt], b, acc[rt][ct], 0, 0, 0);
            }
        }
    }

    // epilogue: add residual, store fp32
#pragma unroll
    for (int rt = 0; rt < 2; ++rt)
#pragma unroll
        for (int ct = 0; ct < 4; ++ct) {
            int rbase = m0 + wr * 32 + rt * 16 + (lane >> 4) * 4;
            int col = n0 + wc * 64 + ct * 16 + (lane & 15);
#pragma unroll
            for (int q = 0; q < 4; ++q) {
                size_t o = (size_t)(rbase + q) * DMODEL + col;
                out[o] = acc[rt][ct][q] + x[o];
            }
        }
}

// ---------------------------------------------------------------- launcher
extern "C" void kernel_launch(void* const* d_in, const int* in_sizes, int n_in,
                              void* d_out, int out_size, void* d_ws, size_t ws_size,
                              hipStream_t stream) {
    const float* x  = (const float*)d_in[0];
    const float* nw = (const float*)d_in[1];
    const float* Wg = (const float*)d_in[2];
    const float* Wu = (const float*)d_in[3];
    const float* Wd = (const float*)d_in[4];
    const float* Wo = (const float*)d_in[5];
    float* out = (float*)d_out;

    char* ws = (char*)d_ws;
    const size_t MB = 1u << 20;
    float* cosT = (float*)(ws);             //  8 MB
    float* sinT = (float*)(ws + 8  * MB);   //  8 MB
    u16*   h    = (u16*)  (ws + 16 * MB);   // 32 MB
    u16*   wgT  = (u16*)  (ws + 48 * MB);   //  1 MB
    u16*   wuT  = (u16*)  (ws + 49 * MB);   //  1 MB
    u16*   wdT  = (u16*)  (ws + 50 * MB);   //  1 MB
    u16*   woT  = (u16*)  (ws + 51 * MB);   //  2 MB
    u16*   dmid = (u16*)  (ws + 53 * MB);   // 32 MB  (end: 85 MB)

    k_rope<<<(S_LEN * 512) / 256, 256, 0, stream>>>(cosT, sinT);
    k_wt<<<(NSUB * DSUB * HFF) / 256, 256, 0, stream>>>(Wg, wgT, NSUB, DSUB, HFF);
    k_wt<<<(NSUB * DSUB * HFF) / 256, 256, 0, stream>>>(Wu, wuT, NSUB, DSUB, HFF);
    k_wt<<<(NSUB * HFF * DSUB) / 256, 256, 0, stream>>>(Wd, wdT, NSUB, HFF, DSUB);
    k_wt<<<(DMODEL * DMODEL) / 256, 256, 0, stream>>>(Wo, woT, 1, DMODEL, DMODEL);
    k_norm_rope<<<NTOK, 256, 0, stream>>>(x, nw, cosT, sinT, h);
    k_swiglu<<<256 * NSUB, 256, 0, stream>>>(h, wgT, wuT, wdT, dmid);
    k_final<<<256 * 8, 256, 0, stream>>>(dmid, woT, x, out);
}

// Round 2
// 283.891 us; speedup vs baseline: 1.5757x; 1.5757x over previous
//
#include <hip/hip_runtime.h>

typedef unsigned short u16;
typedef unsigned int   u32;

typedef float  f32x4  __attribute__((ext_vector_type(4)));
typedef __bf16 bf16x8 __attribute__((ext_vector_type(8)));

#define S_LEN  4096
#define DMODEL 1024
#define NSUB   4
#define DSUB   256
#define HFF    512
#define NTOK   16384   // B*S = 4*4096

static_assert(sizeof(bf16x8) == 16, "frag size");

__device__ __forceinline__ u16 f2bf(float f) {
    union { float f; u32 u; } v; v.f = f;
    u32 r = (v.u + 0x7fffu + ((v.u >> 16) & 1u)) >> 16;   // RNE
    return (u16)r;
}

// ---------------------------------------------------------------- rope table
__global__ __launch_bounds__(256) void k_rope(float* __restrict__ cosT,
                                              float* __restrict__ sinT) {
    int idx = blockIdx.x * 256 + threadIdx.x;        // 4096*512 = 2M threads
    int s = idx >> 9, i = idx & 511;
    const float C = -0.017988945062455435f;          // -2*ln(10000)/1024
    float inv = expf(C * (float)i);
    float ang = (float)s * inv;
    float sn, cs;
    sincosf(ang, &sn, &cs);
    cosT[idx] = cs;
    sinT[idx] = sn;
}

// -------------------------------------------- fragment-packed weight repack
// out[b][C/16][K/32][lane 64][8] = bf16(in[b][k][c]),
//   k = kt*32 + (lane>>4)*8 + j, c = ct*16 + (lane&15)
__global__ __launch_bounds__(256) void k_repack(const float* __restrict__ in,
                                                u16* __restrict__ out,
                                                int Bn, int K, int C) {
    int t = blockIdx.x * 256 + threadIdx.x;
    int total = Bn * (C >> 4) * (K >> 5) * 64;
    if (t >= total) return;
    int lane = t & 63;
    int r = t >> 6;
    int nkt = K >> 5;
    int kt = r % nkt; r /= nkt;
    int nct = C >> 4;
    int ct = r % nct; int b = r / nct;
    int col = ct * 16 + (lane & 15);
    int k0  = kt * 32 + (lane >> 4) * 8;
    const float* src = in + ((size_t)b * K + k0) * C + col;
    union { u16 v[8]; uint4 q; } u;
#pragma unroll
    for (int j = 0; j < 8; ++j) u.v[j] = f2bf(src[(size_t)j * C]);
    *(uint4*)(out + (size_t)t * 8) = u.q;
}

// ---------------------------------------------- fused RMSNorm + RoPE -> bf16
__global__ __launch_bounds__(256) void k_norm_rope(const float* __restrict__ x,
                                                   const float* __restrict__ nw,
                                                   const float* __restrict__ cosT,
                                                   const float* __restrict__ sinT,
                                                   u16* __restrict__ h) {
    int tok = blockIdx.x;
    int s = tok & (S_LEN - 1);
    int t = threadIdx.x;
    const float* xr = x + (size_t)tok * DMODEL;
    float x0 = xr[t], x1 = xr[t + 256], x2 = xr[t + 512], x3 = xr[t + 768];
    float ss = x0 * x0 + x1 * x1 + x2 * x2 + x3 * x3;
#pragma unroll
    for (int o = 32; o > 0; o >>= 1) ss += __shfl_down(ss, o, 64);
    __shared__ float red[4];
    if ((t & 63) == 0) red[t >> 6] = ss;
    __syncthreads();
    float tot = red[0] + red[1] + red[2] + red[3];
    float sc = rsqrtf(tot * (1.0f / DMODEL) + 1e-6f);
    float n0 = x0 * sc * nw[t];
    float n1 = x1 * sc * nw[t + 256];
    float n2 = x2 * sc * nw[t + 512];
    float n3 = x3 * sc * nw[t + 768];
    const float* cr = cosT + (size_t)s * 512;
    const float* sr = sinT + (size_t)s * 512;
    float c0 = cr[t], c1 = cr[t + 256];
    float s0 = sr[t], s1 = sr[t + 256];
    u16* hr = h + (size_t)tok * DMODEL;
    hr[t]       = f2bf(n0 * c0 - n2 * s0);
    hr[t + 256] = f2bf(n1 * c1 - n3 * s1);
    hr[t + 512] = f2bf(n2 * c0 + n0 * s0);
    hr[t + 768] = f2bf(n3 * c1 + n1 * s1);
}

// ---------------------------------------------------------- grouped SwiGLU
// grid: 256 m-blocks x 4 subspaces; 512 thr = 8 waves (2 wr x 4 wc).
// BM=64. H-chunks of 128: gate/up MFMA -> silu*up -> sT[hc&1] -> down MFMA.
// One barrier per chunk (sT double-buffered). Weights fragment-packed,
// register-double-buffered one K-step ahead.
__global__ __launch_bounds__(512) void k_swiglu(const u16* __restrict__ h,
                                                const u16* __restrict__ wgP,   // [4][32][8][64][8]
                                                const u16* __restrict__ wuP,   // [4][32][8][64][8]
                                                const u16* __restrict__ wdP,   // [4][16][16][64][8]
                                                u16* __restrict__ dmid) {
    int bid = blockIdx.x;
    int mb = bid & 255, n = bid >> 8;
    int m0 = mb * 64;
    int tid = threadIdx.x;
    int lane = tid & 63, wid = tid >> 6;
    int wr = wid >> 2, wc = wid & 3;

    __shared__ u16 sA[64 * 256];        // 32KB, swizzled
    __shared__ u16 sT[2][64 * 128];     // 2 x 16KB, swizzled

    // ---- stage h tile [64][256] (subspace n slice), swizzled
    const u16* hbase = h + (size_t)m0 * DMODEL + n * DSUB;
#pragma unroll
    for (int it = 0; it < 4; ++it) {
        int e = (tid + it * 512) * 8;
        int r = e >> 8, c = e & 255;
        uint4 v = *(const uint4*)(hbase + (size_t)r * DMODEL + c);
        u32 off = ((u32)(r * 512 + c * 2)) ^ ((u32)(r & 7) << 4);
        *(uint4*)((char*)sA + off) = v;
    }

    const f32x4 zero = {0.f, 0.f, 0.f, 0.f};
    f32x4 accd[2][4];
#pragma unroll
    for (int a = 0; a < 2; ++a)
#pragma unroll
        for (int b = 0; b < 4; ++b) accd[a][b] = zero;

    const u16* wg = wgP + (size_t)n * 32 * 8 * 512;
    const u16* wu = wuP + (size_t)n * 32 * 8 * 512;
    const u16* wd = wdP + (size_t)n * 16 * 16 * 512;

    __syncthreads();

#pragma unroll
    for (int hc = 0; hc < 4; ++hc) {
        // ======== gate/up for chunk [64 x 128]
        f32x4 accg[2][2], accu[2][2];
#pragma unroll
        for (int a = 0; a < 2; ++a)
#pragma unroll
            for (int b = 0; b < 2; ++b) { accg[a][b] = zero; accu[a][b] = zero; }

        bf16x8 bg[2][2], bu[2][2];      // [buf][ct]
#pragma unroll
        for (int ct = 0; ct < 2; ++ct) {
            size_t ctile = (size_t)(hc * 8 + wc * 2 + ct);
            bg[0][ct] = *(const bf16x8*)(wg + (ctile * 8 + 0) * 512 + lane * 8);
            bu[0][ct] = *(const bf16x8*)(wu + (ctile * 8 + 0) * 512 + lane * 8);
        }
#pragma unroll
        for (int ks = 0; ks < 8; ++ks) {
            if (ks < 7) {
#pragma unroll
                for (int ct = 0; ct < 2; ++ct) {
                    size_t ctile = (size_t)(hc * 8 + wc * 2 + ct);
                    bg[(ks + 1) & 1][ct] = *(const bf16x8*)(wg + (ctile * 8 + ks + 1) * 512 + lane * 8);
                    bu[(ks + 1) & 1][ct] = *(const bf16x8*)(wu + (ctile * 8 + ks + 1) * 512 + lane * 8);
                }
            }
            bf16x8 afr[2];
#pragma unroll
            for (int rt = 0; rt < 2; ++rt) {
                int arow = wr * 32 + rt * 16 + (lane & 15);
                int k0 = ks * 32 + (lane >> 4) * 8;
                u32 off = ((u32)(arow * 512 + k0 * 2)) ^ ((u32)(arow & 7) << 4);
                afr[rt] = *(const bf16x8*)((const char*)sA + off);
            }
#pragma unroll
            for (int ct = 0; ct < 2; ++ct)
#pragma unroll
                for (int rt = 0; rt < 2; ++rt) {
                    accg[rt][ct] = __builtin_amdgcn_mfma_f32_16x16x32_bf16(afr[rt], bg[ks & 1][ct], accg[rt][ct], 0, 0, 0);
                    accu[rt][ct] = __builtin_amdgcn_mfma_f32_16x16x32_bf16(afr[rt], bu[ks & 1][ct], accu[rt][ct], 0, 0, 0);
                }
        }

        // ======== t = silu(gate)*up -> sT[hc&1] (swizzled scatter)
        u16* sTc = (u16*)sT[hc & 1];
#pragma unroll
        for (int rt = 0; rt < 2; ++rt)
#pragma unroll
            for (int ct = 0; ct < 2; ++ct) {
                int rbase = wr * 32 + rt * 16 + (lane >> 4) * 4;
                int col = wc * 32 + ct * 16 + (lane & 15);
#pragma unroll
                for (int q = 0; q < 4; ++q) {
                    float g = accg[rt][ct][q], u = accu[rt][ct][q];
                    float tv = (g / (1.0f + __expf(-g))) * u;
                    int row = rbase + q;
                    u32 off = ((u32)(row * 256 + col * 2)) ^ ((u32)(row & 7) << 4);
                    *(u16*)((char*)sTc + off) = f2bf(tv);
                }
            }

        __syncthreads();

        // ======== down accumulation over this chunk's K=128
        bf16x8 bd[2][4];
#pragma unroll
        for (int ct = 0; ct < 4; ++ct) {
            size_t ctile = (size_t)(wc * 4 + ct);
            size_t ktile = (size_t)(hc * 4 + 0);
            bd[0][ct] = *(const bf16x8*)(wd + (ctile * 16 + ktile) * 512 + lane * 8);
        }
#pragma unroll
        for (int k2 = 0; k2 < 4; ++k2) {
            if (k2 < 3) {
#pragma unroll
                for (int ct = 0; ct < 4; ++ct) {
                    size_t ctile = (size_t)(wc * 4 + ct);
                    size_t ktile = (size_t)(hc * 4 + k2 + 1);
                    bd[(k2 + 1) & 1][ct] = *(const bf16x8*)(wd + (ctile * 16 + ktile) * 512 + lane * 8);
                }
            }
            bf16x8 afr[2];
#pragma unroll
            for (int rt = 0; rt < 2; ++rt) {
                int arow = wr * 32 + rt * 16 + (lane & 15);
                int k0 = k2 * 32 + (lane >> 4) * 8;
                u32 off = ((u32)(arow * 256 + k0 * 2)) ^ ((u32)(arow & 7) << 4);
                afr[rt] = *(const bf16x8*)((const char*)sTc + off);
            }
#pragma unroll
            for (int ct = 0; ct < 4; ++ct)
#pragma unroll
                for (int rt = 0; rt < 2; ++rt)
                    accd[rt][ct] = __builtin_amdgcn_mfma_f32_16x16x32_bf16(afr[rt], bd[k2 & 1][ct], accd[rt][ct], 0, 0, 0);
        }
    }

    // ---- write dmid [64][256] n-slice as bf16
#pragma unroll
    for (int rt = 0; rt < 2; ++rt)
#pragma unroll
        for (int ct = 0; ct < 4; ++ct) {
            int rbase = m0 + wr * 32 + rt * 16 + (lane >> 4) * 4;
            int col = n * DSUB + wc * 64 + ct * 16 + (lane & 15);
#pragma unroll
            for (int q = 0; q < 4; ++q)
                dmid[(size_t)(rbase + q) * DMODEL + col] = f2bf(accd[rt][ct][q]);
        }
}

// -------------------------------------------------- final GEMM + residual
// grid: 256 m-blocks x 4 n-blocks; BM=64, BN=256; 512 thr = 8 waves (2x4).
// sA double-buffered, T14-split staging; Wo fragment-packed + reg prefetch.
__global__ __launch_bounds__(512) void k_final(const u16* __restrict__ dmid,
                                               const u16* __restrict__ woP,   // [64][32][64][8]
                                               const float* __restrict__ x,
                                               float* __restrict__ out) {
    int bid = blockIdx.x;
    int mb = bid & 255, nb = bid >> 8;
    int m0 = mb * 64, n0 = nb * 256;
    int tid = threadIdx.x;
    int lane = tid & 63, wid = tid >> 6;
    int wr = wid >> 2, wc = wid & 3;

    __shared__ u16 sA[2][64 * 256];     // 2 x 32KB, swizzled

    const f32x4 zero = {0.f, 0.f, 0.f, 0.f};
    f32x4 acc[2][4];
#pragma unroll
    for (int a = 0; a < 2; ++a)
#pragma unroll
        for (int b = 0; b < 4; ++b) acc[a][b] = zero;

    const u16* dbase = dmid + (size_t)m0 * DMODEL;
    int se = (tid) * 8;                 // staging element base (it adds 512*8)

    uint4 st0[4], st1[4];
    // chunk 0 -> st0, write sA[0]
#pragma unroll
    for (int it = 0; it < 4; ++it) {
        int e = se + it * 4096;
        int r = e >> 8, c = e & 255;
        st0[it] = *(const uint4*)(dbase + (size_t)r * DMODEL + c);
    }
#pragma unroll
    for (int it = 0; it < 4; ++it) {
        int e = se + it * 4096;
        int r = e >> 8, c = e & 255;
        u32 off = ((u32)(r * 512 + c * 2)) ^ ((u32)(r & 7) << 4);
        *(uint4*)((char*)sA[0] + off) = st0[it];
    }
    // issue chunk 1 -> st1
#pragma unroll
    for (int it = 0; it < 4; ++it) {
        int e = se + it * 4096;
        int r = e >> 8, c = e & 255;
        st1[it] = *(const uint4*)(dbase + (size_t)r * DMODEL + 256 + c);
    }

#pragma unroll
    for (int kc = 0; kc < 4; ++kc) {
        __syncthreads();                       // sA[kc&1] ready
        if (kc < 3) {                          // write sA[(kc+1)&1] from regs
#pragma unroll
            for (int it = 0; it < 4; ++it) {
                int e = se + it * 4096;
                int r = e >> 8, c = e & 255;
                u32 off = ((u32)(r * 512 + c * 2)) ^ ((u32)(r & 7) << 4);
                uint4 v = ((kc + 1) & 1) ? st1[it] : st0[it];
                *(uint4*)((char*)sA[(kc + 1) & 1] + off) = v;
            }
        }
        if (kc < 2) {                          // issue chunk kc+2 into free set
#pragma unroll
            for (int it = 0; it < 4; ++it) {
                int e = se + it * 4096;
                int r = e >> 8, c = e & 255;
                uint4 v = *(const uint4*)(dbase + (size_t)r * DMODEL + (kc + 2) * 256 + c);
                if ((kc & 1) == 0) st0[it] = v; else st1[it] = v;
            }
        }

        const u16* sAc = (const u16*)sA[kc & 1];
        bf16x8 wf[2][4];
#pragma unroll
        for (int ct = 0; ct < 4; ++ct) {
            size_t ctile = (size_t)(nb * 16 + wc * 4 + ct);
            size_t ktile = (size_t)(kc * 8 + 0);
            wf[0][ct] = *(const bf16x8*)(woP + (ctile * 32 + ktile) * 512 + lane * 8);
        }
#pragma unroll
        for (int ks = 0; ks < 8; ++ks) {
            if (ks < 7) {
#pragma unroll
                for (int ct = 0; ct < 4; ++ct) {
                    size_t ctile = (size_t)(nb * 16 + wc * 4 + ct);
                    size_t ktile = (size_t)(kc * 8 + ks + 1);
                    wf[(ks + 1) & 1][ct] = *(const bf16x8*)(woP + (ctile * 32 + ktile) * 512 + lane * 8);
                }
            }
            bf16x8 afr[2];
#pragma unroll
            for (int rt = 0; rt < 2; ++rt) {
                int arow = wr * 32 + rt * 16 + (lane & 15);
                int k0 = ks * 32 + (lane >> 4) * 8;
                u32 off = ((u32)(arow * 512 + k0 * 2)) ^ ((u32)(arow & 7) << 4);
                afr[rt] = *(const bf16x8*)((const char*)sAc + off);
            }
#pragma unroll
            for (int ct = 0; ct < 4; ++ct)
#pragma unroll
                for (int rt = 0; rt < 2; ++rt)
                    acc[rt][ct] = __builtin_amdgcn_mfma_f32_16x16x32_bf16(afr[rt], wf[ks & 1][ct], acc[rt][ct], 0, 0, 0);
        }
    }

    // epilogue: residual add, fp32 store
#pragma unroll
    for (int rt = 0; rt < 2; ++rt)
#pragma unroll
        for (int ct = 0; ct < 4; ++ct) {
            int rbase = m0 + wr * 32 + rt * 16 + (lane >> 4) * 4;
            int col = n0 + wc * 64 + ct * 16 + (lane & 15);
#pragma unroll
            for (int q = 0; q < 4; ++q) {
                size_t o = (size_t)(rbase + q) * DMODEL + col;
                out[o] = acc[rt][ct][q] + x[o];
            }
        }
}

// ---------------------------------------------------------------- launcher
extern "C" void kernel_launch(void* const* d_in, const int* in_sizes, int n_in,
                              void* d_out, int out_size, void* d_ws, size_t ws_size,
                              hipStream_t stream) {
    const float* x  = (const float*)d_in[0];
    const float* nw = (const float*)d_in[1];
    const float* Wg = (const float*)d_in[2];
    const float* Wu = (const float*)d_in[3];
    const float* Wd = (const float*)d_in[4];
    const float* Wo = (const float*)d_in[5];
    float* out = (float*)d_out;

    char* ws = (char*)d_ws;
    const size_t MB = 1u << 20;
    float* cosT = (float*)(ws);             //  8 MB
    float* sinT = (float*)(ws + 8  * MB);   //  8 MB
    u16*   h    = (u16*)  (ws + 16 * MB);   // 32 MB
    u16*   wgP  = (u16*)  (ws + 48 * MB);   //  1 MB
    u16*   wuP  = (u16*)  (ws + 49 * MB);   //  1 MB
    u16*   wdP  = (u16*)  (ws + 50 * MB);   //  1 MB
    u16*   woP  = (u16*)  (ws + 51 * MB);   //  2 MB
    u16*   dmid = (u16*)  (ws + 53 * MB);   // 32 MB  (end: 85 MB)

    k_rope<<<(S_LEN * 512) / 256, 256, 0, stream>>>(cosT, sinT);
    k_repack<<<(NSUB * 32 * 8 * 64) / 256, 256, 0, stream>>>(Wg, wgP, NSUB, DSUB, HFF);
    k_repack<<<(NSUB * 32 * 8 * 64) / 256, 256, 0, stream>>>(Wu, wuP, NSUB, DSUB, HFF);
    k_repack<<<(NSUB * 16 * 16 * 64) / 256, 256, 0, stream>>>(Wd, wdP, NSUB, HFF, DSUB);
    k_repack<<<(64 * 32 * 64) / 256, 256, 0, stream>>>(Wo, woP, 1, DMODEL, DMODEL);
    k_norm_rope<<<NTOK, 256, 0, stream>>>(x, nw, cosT, sinT, h);
    k_swiglu<<<256 * NSUB, 512, 0, stream>>>(h, wgP, wuP, wdP, dmid);
    k_final<<<256 * 4, 512, 0, stream>>>(dmid, woP, x, out);
}

// Round 3
// 204.808 us; speedup vs baseline: 2.1841x; 1.3861x over previous
//
#include <hip/hip_runtime.h>

typedef unsigned short u16;
typedef unsigned int   u32;

typedef float  f32x4  __attribute__((ext_vector_type(4)));
typedef __bf16 bf16x8 __attribute__((ext_vector_type(8)));

#define S_LEN  4096
#define DMODEL 1024
#define NSUB   4
#define DSUB   256
#define HFF    512
#define NTOK   16384   // B*S = 4*4096

static_assert(sizeof(bf16x8) == 16, "frag size");

__device__ __forceinline__ u16 f2bf(float f) {
    union { float f; u32 u; } v; v.f = f;
    u32 r = (v.u + 0x7fffu + ((v.u >> 16) & 1u)) >> 16;   // RNE
    return (u16)r;
}

// -------------------------------------------- fused fragment-packed repack
// dst[b][C/16][K/32][lane 64][8] = bf16(src[b][k][c]),
//   k = kt*32 + (lane>>4)*8 + j, c = ct*16 + (lane&15)
// Segments (block-uniform): [0,65536) Wg, [65536,131072) Wu,
// [131072,196608) Wd, [196608,327680) Wo.
__global__ __launch_bounds__(512) void k_repack_all(const float* __restrict__ Wg,
                                                    const float* __restrict__ Wu,
                                                    const float* __restrict__ Wd,
                                                    const float* __restrict__ Wo,
                                                    u16* __restrict__ wgP,
                                                    u16* __restrict__ wuP,
                                                    u16* __restrict__ wdP,
                                                    u16* __restrict__ woP) {
    int t = blockIdx.x * 512 + threadIdx.x;
    const float* src; u16* dst; int K, C, rel;
    if (t < 65536)       { src = Wg; dst = wgP; K = 256;  C = 512;  rel = t; }
    else if (t < 131072) { src = Wu; dst = wuP; K = 256;  C = 512;  rel = t - 65536; }
    else if (t < 196608) { src = Wd; dst = wdP; K = 512;  C = 256;  rel = t - 131072; }
    else                 { src = Wo; dst = woP; K = 1024; C = 1024; rel = t - 196608; }
    int lane = rel & 63;
    int f = rel >> 6;
    int nkt = K >> 5;
    int kt = f % nkt; int f2 = f / nkt;
    int nct = C >> 4;
    int ct = f2 % nct; int b = f2 / nct;
    int col = ct * 16 + (lane & 15);
    int k0  = kt * 32 + (lane >> 4) * 8;
    const float* s = src + ((size_t)b * K + k0) * C + col;
    union { u16 v[8]; uint4 q; } u;
#pragma unroll
    for (int j = 0; j < 8; ++j) u.v[j] = f2bf(s[(size_t)j * C]);
    *(uint4*)(dst + (size_t)rel * 8) = u.q;
}

// ------------------------- fused RMSNorm + RoPE (inline trig) -> bf16 h
__global__ __launch_bounds__(256) void k_norm_rope(const float* __restrict__ x,
                                                   const float* __restrict__ nw,
                                                   u16* __restrict__ h) {
    int tok = blockIdx.x;
    int s = tok & (S_LEN - 1);
    int t = threadIdx.x;
    const float* xr = x + (size_t)tok * DMODEL;
    float x0 = xr[t], x1 = xr[t + 256], x2 = xr[t + 512], x3 = xr[t + 768];
    float ss = x0 * x0 + x1 * x1 + x2 * x2 + x3 * x3;
#pragma unroll
    for (int o = 32; o > 0; o >>= 1) ss += __shfl_down(ss, o, 64);
    __shared__ float red[4];
    if ((t & 63) == 0) red[t >> 6] = ss;
    __syncthreads();
    float tot = red[0] + red[1] + red[2] + red[3];
    float sc = rsqrtf(tot * (1.0f / DMODEL) + 1e-6f);
    float n0 = x0 * sc * nw[t];
    float n1 = x1 * sc * nw[t + 256];
    float n2 = x2 * sc * nw[t + 512];
    float n3 = x3 * sc * nw[t + 768];
    // inv_freq = 10000^(-i/512) = exp(C*i), C = -ln(10000)/512
    const float C = -0.017988946039015984f;
    float sf = (float)s;
    float ang0 = sf * expf(C * (float)t);
    float ang1 = sf * expf(C * (float)(t + 256));
    float sn0, cs0, sn1, cs1;
    sincosf(ang0, &sn0, &cs0);
    sincosf(ang1, &sn1, &cs1);
    u16* hr = h + (size_t)tok * DMODEL;
    hr[t]       = f2bf(n0 * cs0 - n2 * sn0);
    hr[t + 256] = f2bf(n1 * cs1 - n3 * sn1);
    hr[t + 512] = f2bf(n2 * cs0 + n0 * sn0);
    hr[t + 768] = f2bf(n3 * cs1 + n1 * sn1);
}

// ---------------------------------------------------------- grouped SwiGLU
// grid: 128 m-blocks x 4 subspaces; 512 thr = 8 waves (2 wr x 4 wc).
// BM=128. H-chunks of 128: gate/up MFMA -> silu*up -> sT[hc&1] -> down MFMA.
// One barrier per chunk. Weights fragment-packed, reg-prefetched 1 K-step.
__global__ __launch_bounds__(512, 2) void k_swiglu(const u16* __restrict__ h,
                                                   const u16* __restrict__ wgP,   // [4][32][8][64][8]
                                                   const u16* __restrict__ wuP,   // [4][32][8][64][8]
                                                   const u16* __restrict__ wdP,   // [4][16][16][64][8]
                                                   u16* __restrict__ dmid) {
    int bid = blockIdx.x;
    int mb = bid & 127, n = bid >> 7;
    int m0 = mb * 128;
    int tid = threadIdx.x;
    int lane = tid & 63, wid = tid >> 6;
    int wr = wid >> 2, wc = wid & 3;

    __shared__ u16 sA[128 * 256];        // 64KB, swizzled
    __shared__ u16 sT[2][128 * 128];     // 2 x 32KB, swizzled

    // ---- stage h tile [128][256] (subspace n slice), swizzled
    const u16* hbase = h + (size_t)m0 * DMODEL + n * DSUB;
#pragma unroll
    for (int it = 0; it < 8; ++it) {
        int e = (tid + it * 512) * 8;
        int r = e >> 8, c = e & 255;
        uint4 v = *(const uint4*)(hbase + (size_t)r * DMODEL + c);
        u32 off = ((u32)(r * 512 + c * 2)) ^ ((u32)(r & 7) << 4);
        *(uint4*)((char*)sA + off) = v;
    }

    const f32x4 zero = {0.f, 0.f, 0.f, 0.f};
    f32x4 accd[4][4];
#pragma unroll
    for (int a = 0; a < 4; ++a)
#pragma unroll
        for (int b = 0; b < 4; ++b) accd[a][b] = zero;

    const u16* wg = wgP + (size_t)n * (32 * 8 * 512);
    const u16* wu = wuP + (size_t)n * (32 * 8 * 512);
    const u16* wd = wdP + (size_t)n * (16 * 16 * 512);

    __syncthreads();

#pragma unroll
    for (int hc = 0; hc < 4; ++hc) {
        // ======== gate/up for chunk [128 x 128]
        f32x4 accg[4][2], accu[4][2];
#pragma unroll
        for (int a = 0; a < 4; ++a)
#pragma unroll
            for (int b = 0; b < 2; ++b) { accg[a][b] = zero; accu[a][b] = zero; }

        bf16x8 bg[2][2], bu[2][2];      // [buf][ct]
#pragma unroll
        for (int ct = 0; ct < 2; ++ct) {
            size_t ctile = (size_t)(hc * 8 + wc * 2 + ct);
            bg[0][ct] = *(const bf16x8*)(wg + (ctile * 8 + 0) * 512 + lane * 8);
            bu[0][ct] = *(const bf16x8*)(wu + (ctile * 8 + 0) * 512 + lane * 8);
        }
#pragma unroll
        for (int ks = 0; ks < 8; ++ks) {
            if (ks < 7) {
#pragma unroll
                for (int ct = 0; ct < 2; ++ct) {
                    size_t ctile = (size_t)(hc * 8 + wc * 2 + ct);
                    bg[(ks + 1) & 1][ct] = *(const bf16x8*)(wg + (ctile * 8 + ks + 1) * 512 + lane * 8);
                    bu[(ks + 1) & 1][ct] = *(const bf16x8*)(wu + (ctile * 8 + ks + 1) * 512 + lane * 8);
                }
            }
            bf16x8 afr[4];
#pragma unroll
            for (int rt = 0; rt < 4; ++rt) {
                int arow = wr * 64 + rt * 16 + (lane & 15);
                int k0 = ks * 32 + (lane >> 4) * 8;
                u32 off = ((u32)(arow * 512 + k0 * 2)) ^ ((u32)(arow & 7) << 4);
                afr[rt] = *(const bf16x8*)((const char*)sA + off);
            }
#pragma unroll
            for (int ct = 0; ct < 2; ++ct)
#pragma unroll
                for (int rt = 0; rt < 4; ++rt) {
                    accg[rt][ct] = __builtin_amdgcn_mfma_f32_16x16x32_bf16(afr[rt], bg[ks & 1][ct], accg[rt][ct], 0, 0, 0);
                    accu[rt][ct] = __builtin_amdgcn_mfma_f32_16x16x32_bf16(afr[rt], bu[ks & 1][ct], accu[rt][ct], 0, 0, 0);
                }
        }

        // ======== t = silu(gate)*up -> sT[hc&1] (swizzled scatter)
        u16* sTc = (u16*)sT[hc & 1];
#pragma unroll
        for (int rt = 0; rt < 4; ++rt)
#pragma unroll
            for (int ct = 0; ct < 2; ++ct) {
                int rbase = wr * 64 + rt * 16 + (lane >> 4) * 4;
                int col = (wc * 2 + ct) * 16 + (lane & 15);
#pragma unroll
                for (int q = 0; q < 4; ++q) {
                    float g = accg[rt][ct][q], u = accu[rt][ct][q];
                    float tv = (g / (1.0f + __expf(-g))) * u;
                    int row = rbase + q;
                    u32 off = ((u32)(row * 256 + col * 2)) ^ ((u32)(row & 7) << 4);
                    *(u16*)((char*)sTc + off) = f2bf(tv);
                }
            }

        __syncthreads();

        // ======== down accumulation over this chunk's K=128
        bf16x8 bd[2][4];
#pragma unroll
        for (int ct = 0; ct < 4; ++ct) {
            size_t ctile = (size_t)(wc * 4 + ct);
            size_t ktile = (size_t)(hc * 4 + 0);
            bd[0][ct] = *(const bf16x8*)(wd + (ctile * 16 + ktile) * 512 + lane * 8);
        }
#pragma unroll
        for (int k2 = 0; k2 < 4; ++k2) {
            if (k2 < 3) {
#pragma unroll
                for (int ct = 0; ct < 4; ++ct) {
                    size_t ctile = (size_t)(wc * 4 + ct);
                    size_t ktile = (size_t)(hc * 4 + k2 + 1);
                    bd[(k2 + 1) & 1][ct] = *(const bf16x8*)(wd + (ctile * 16 + ktile) * 512 + lane * 8);
                }
            }
            bf16x8 afr[4];
#pragma unroll
            for (int rt = 0; rt < 4; ++rt) {
                int arow = wr * 64 + rt * 16 + (lane & 15);
                int k0 = k2 * 32 + (lane >> 4) * 8;
                u32 off = ((u32)(arow * 256 + k0 * 2)) ^ ((u32)(arow & 7) << 4);
                afr[rt] = *(const bf16x8*)((const char*)sTc + off);
            }
#pragma unroll
            for (int ct = 0; ct < 4; ++ct)
#pragma unroll
                for (int rt = 0; rt < 4; ++rt)
                    accd[rt][ct] = __builtin_amdgcn_mfma_f32_16x16x32_bf16(afr[rt], bd[k2 & 1][ct], accd[rt][ct], 0, 0, 0);
        }
    }

    // ---- write dmid [128][256] n-slice as bf16
#pragma unroll
    for (int rt = 0; rt < 4; ++rt)
#pragma unroll
        for (int ct = 0; ct < 4; ++ct) {
            int rbase = m0 + wr * 64 + rt * 16 + (lane >> 4) * 4;
            int col = n * DSUB + wc * 64 + ct * 16 + (lane & 15);
#pragma unroll
            for (int q = 0; q < 4; ++q)
                dmid[(size_t)(rbase + q) * DMODEL + col] = f2bf(accd[rt][ct][q]);
        }
}

// -------------------------------------------------- final GEMM + residual
// grid: 128 m-blocks x 4 n-blocks; BM=128, BN=256; 512 thr = 8 waves (2x4).
// sA double-buffered, split reg staging; Wo fragment-packed + reg prefetch.
__global__ __launch_bounds__(512, 2) void k_final(const u16* __restrict__ dmid,
                                                  const u16* __restrict__ woP,   // [64][32][64][8]
                                                  const float* __restrict__ x,
                                                  float* __restrict__ out) {
    int bid = blockIdx.x;
    int mb = bid & 127, nb = bid >> 7;
    int m0 = mb * 128, n0 = nb * 256;
    int tid = threadIdx.x;
    int lane = tid & 63, wid = tid >> 6;
    int wr = wid >> 2, wc = wid & 3;

    __shared__ u16 sA[2][128 * 256];     // 2 x 64KB, swizzled

    const f32x4 zero = {0.f, 0.f, 0.f, 0.f};
    f32x4 acc[4][4];
#pragma unroll
    for (int a = 0; a < 4; ++a)
#pragma unroll
        for (int b = 0; b < 4; ++b) acc[a][b] = zero;

    const u16* dbase = dmid + (size_t)m0 * DMODEL;

    uint4 stA[8], stB[8];
    // chunk 0 -> stA, write sA[0]
#pragma unroll
    for (int it = 0; it < 8; ++it) {
        int e = (tid + it * 512) * 8;
        int r = e >> 8, c = e & 255;
        stA[it] = *(const uint4*)(dbase + (size_t)r * DMODEL + c);
    }
#pragma unroll
    for (int it = 0; it < 8; ++it) {
        int e = (tid + it * 512) * 8;
        int r = e >> 8, c = e & 255;
        u32 off = ((u32)(r * 512 + c * 2)) ^ ((u32)(r & 7) << 4);
        *(uint4*)((char*)sA[0] + off) = stA[it];
    }
    // issue chunk 1 -> stB
#pragma unroll
    for (int it = 0; it < 8; ++it) {
        int e = (tid + it * 512) * 8;
        int r = e >> 8, c = e & 255;
        stB[it] = *(const uint4*)(dbase + (size_t)r * DMODEL + 256 + c);
    }

#pragma unroll
    for (int kc = 0; kc < 4; ++kc) {
        __syncthreads();                       // sA[kc&1] ready
        if (kc < 3) {                          // write chunk kc+1 into sA[(kc+1)&1]
#pragma unroll
            for (int it = 0; it < 8; ++it) {
                int e = (tid + it * 512) * 8;
                int r = e >> 8, c = e & 255;
                u32 off = ((u32)(r * 512 + c * 2)) ^ ((u32)(r & 7) << 4);
                uint4 v = (kc & 1) ? stA[it] : stB[it];
                *(uint4*)((char*)sA[(kc + 1) & 1] + off) = v;
            }
        }
        if (kc < 2) {                          // issue chunk kc+2
#pragma unroll
            for (int it = 0; it < 8; ++it) {
                int e = (tid + it * 512) * 8;
                int r = e >> 8, c = e & 255;
                uint4 v = *(const uint4*)(dbase + (size_t)r * DMODEL + (kc + 2) * 256 + c);
                if ((kc & 1) == 0) stA[it] = v; else stB[it] = v;
            }
        }

        const u16* sAc = (const u16*)sA[kc & 1];
        bf16x8 wf[2][4];
#pragma unroll
        for (int ct = 0; ct < 4; ++ct) {
            size_t ctile = (size_t)(nb * 16 + wc * 4 + ct);
            size_t ktile = (size_t)(kc * 8 + 0);
            wf[0][ct] = *(const bf16x8*)(woP + (ctile * 32 + ktile) * 512 + lane * 8);
        }
#pragma unroll
        for (int ks = 0; ks < 8; ++ks) {
            if (ks < 7) {
#pragma unroll
                for (int ct = 0; ct < 4; ++ct) {
                    size_t ctile = (size_t)(nb * 16 + wc * 4 + ct);
                    size_t ktile = (size_t)(kc * 8 + ks + 1);
                    wf[(ks + 1) & 1][ct] = *(const bf16x8*)(woP + (ctile * 32 + ktile) * 512 + lane * 8);
                }
            }
            bf16x8 afr[4];
#pragma unroll
            for (int rt = 0; rt < 4; ++rt) {
                int arow = wr * 64 + rt * 16 + (lane & 15);
                int k0 = ks * 32 + (lane >> 4) * 8;
                u32 off = ((u32)(arow * 512 + k0 * 2)) ^ ((u32)(arow & 7) << 4);
                afr[rt] = *(const bf16x8*)((const char*)sAc + off);
            }
#pragma unroll
            for (int ct = 0; ct < 4; ++ct)
#pragma unroll
                for (int rt = 0; rt < 4; ++rt)
                    acc[rt][ct] = __builtin_amdgcn_mfma_f32_16x16x32_bf16(afr[rt], wf[ks & 1][ct], acc[rt][ct], 0, 0, 0);
        }
    }

    // epilogue: residual add, fp32 store
#pragma unroll
    for (int rt = 0; rt < 4; ++rt)
#pragma unroll
        for (int ct = 0; ct < 4; ++ct) {
            int rbase = m0 + wr * 64 + rt * 16 + (lane >> 4) * 4;
            int col = n0 + wc * 64 + ct * 16 + (lane & 15);
#pragma unroll
            for (int q = 0; q < 4; ++q) {
                size_t o = (size_t)(rbase + q) * DMODEL + col;
                out[o] = acc[rt][ct][q] + x[o];
            }
        }
}

// ---------------------------------------------------------------- launcher
extern "C" void kernel_launch(void* const* d_in, const int* in_sizes, int n_in,
                              void* d_out, int out_size, void* d_ws, size_t ws_size,
                              hipStream_t stream) {
    const float* x  = (const float*)d_in[0];
    const float* nw = (const float*)d_in[1];
    const float* Wg = (const float*)d_in[2];
    const float* Wu = (const float*)d_in[3];
    const float* Wd = (const float*)d_in[4];
    const float* Wo = (const float*)d_in[5];
    float* out = (float*)d_out;

    char* ws = (char*)d_ws;
    const size_t MB = 1u << 20;
    u16* h    = (u16*)(ws);             // 32 MB
    u16* wgP  = (u16*)(ws + 32 * MB);   //  1 MB
    u16* wuP  = (u16*)(ws + 33 * MB);   //  1 MB
    u16* wdP  = (u16*)(ws + 34 * MB);   //  1 MB
    u16* woP  = (u16*)(ws + 35 * MB);   //  2 MB
    u16* dmid = (u16*)(ws + 37 * MB);   // 32 MB  (end: 69 MB)

    k_repack_all<<<640, 512, 0, stream>>>(Wg, Wu, Wd, Wo, wgP, wuP, wdP, woP);
    k_norm_rope<<<NTOK, 256, 0, stream>>>(x, nw, h);
    k_swiglu<<<128 * NSUB, 512, 0, stream>>>(h, wgP, wuP, wdP, dmid);
    k_final<<<128 * 4, 512, 0, stream>>>(dmid, woP, x, out);
}